// Round 3
// baseline (282.744 us; speedup 1.0000x reference)
//
#include <hip/hip_runtime.h>
#include <hip/hip_bf16.h>
#include <stdint.h>

#define M_DIM 8192   // 4*2048
#define N_DIM 4096   // OUT_FEATURES
#define K_DIM 4096   // IN_FEATURES
#define KB2   (K_DIM * 2)   // bytes per K-row

typedef __attribute__((ext_vector_type(8))) __bf16 bf16x8;
typedef __attribute__((ext_vector_type(4))) float  f32x4;

#define GLD_LDS16(gaddr, laddr)                                            \
  __builtin_amdgcn_global_load_lds(                                        \
      (const __attribute__((address_space(1))) uint32_t*)(gaddr),          \
      (__attribute__((address_space(3))) uint32_t*)(laddr), 16, 0, 0)

// ---------------------------------------------------------------------------
// Dequant: qweight (8, O, 128) int32 bit-planes + lut (O,16) -> Wb (O,K) bf16
// ---------------------------------------------------------------------------
__global__ __launch_bounds__(256) void anyprec_dequant_kernel(
    const int* __restrict__ q, const float* __restrict__ lut,
    __bf16* __restrict__ Wb) {
  int t = blockIdx.x * 256 + threadIdx.x;   // 0 .. O*128-1
  int o = t >> 7;
  int w = t & 127;
  const int PLANE = N_DIM * (K_DIM / 32);
  int base = o * (K_DIM / 32) + w;
  uint32_t q0 = (uint32_t)q[0 * PLANE + base];
  uint32_t q1 = (uint32_t)q[1 * PLANE + base];
  uint32_t q2 = (uint32_t)q[2 * PLANE + base];
  uint32_t q3 = (uint32_t)q[3 * PLANE + base];
  const float* lrow = lut + o * 16;

  __bf16 vals[32];
#pragma unroll
  for (int i = 0; i < 32; ++i) {
    uint32_t idx = ((q0 >> i) & 1u) | (((q1 >> i) & 1u) << 1) |
                   (((q2 >> i) & 1u) << 2) | (((q3 >> i) & 1u) << 3);
    vals[i] = (__bf16)lrow[idx];
  }
  bf16x8* dst = (bf16x8*)(Wb + (size_t)o * K_DIM + w * 32);
#pragma unroll
  for (int r = 0; r < 4; ++r) {
    bf16x8 v;
#pragma unroll
    for (int j = 0; j < 8; ++j) v[j] = vals[r * 8 + j];
    dst[r] = v;
  }
}

// ---------------------------------------------------------------------------
// x fp32 -> bf16
// ---------------------------------------------------------------------------
__global__ __launch_bounds__(256) void cvt_x_kernel(
    const float* __restrict__ x, __bf16* __restrict__ xb, int n8) {
  int t = blockIdx.x * 256 + threadIdx.x;
  if (t >= n8) return;
  f32x4 a = ((const f32x4*)x)[t * 2];
  f32x4 b = ((const f32x4*)x)[t * 2 + 1];
  bf16x8 v;
  v[0] = (__bf16)a[0]; v[1] = (__bf16)a[1]; v[2] = (__bf16)a[2]; v[3] = (__bf16)a[3];
  v[4] = (__bf16)b[0]; v[5] = (__bf16)b[1]; v[6] = (__bf16)b[2]; v[7] = (__bf16)b[3];
  ((bf16x8*)xb)[t] = v;
}

// ---------------------------------------------------------------------------
// 256x256 8-phase bf16 GEMM: C[M,N] = A[M,K] * B[N,K]^T + bias (fp32 out)
// 512 thr = 8 waves (2M x 4N). BK=64. LDS 128 KiB: [buf][A/B][half][128x64].
// R3 schedule: every half-tile staged >=4 phases before its drain; drains
// are vmcnt(6) (3 stages in flight) at ph4/ph8 only.
//   stages: ph1=B0(t1) ph2=A0(t2) ph4=A1(t2),B1(t2) ph5=B0(t2)
//           ph6=A0(t3) ph8=A1(t3),B1(t3)
// ---------------------------------------------------------------------------
__global__ __launch_bounds__(512, 2) void anyprec_gemm_kernel(
    const __bf16* __restrict__ A,   // M x K bf16
    const __bf16* __restrict__ B,   // N x K bf16
    const float* __restrict__ bias,
    float* __restrict__ C) {
  __shared__ __bf16 lds[2][2][2][128 * 64];   // 131072 B

  // XCD-aware bijective swizzle (512 wgs, 512%8==0)
  int bid = blockIdx.x;
  int swz = (bid & 7) * 64 + (bid >> 3);
  int mb = swz >> 4;    // 32 m-tiles
  int nb = swz & 15;    // 16 n-tiles

  const int tid  = threadIdx.x;
  const int lane = tid & 63;
  const int wid  = tid >> 6;
  const int wr   = wid >> 2;   // 0..1
  const int wc   = wid & 3;    // 0..3

  const char* gA = (const char*)A + (size_t)mb * 256 * KB2;
  const char* gB = (const char*)B + (size_t)nb * 256 * KB2;
  const size_t gro0 = (size_t)(tid >> 3) * KB2;       // row  = chunk>>3
  const size_t gro1 = gro0 + (size_t)64 * KB2;        // row + 64
  const int    scx  = (((tid & 7) ^ ((tid >> 3) & 7)) << 4);  // swizzled src chunk
  const int    lt0  = tid * 16;
  const int    lt1  = tid * 16 + 8192;

  const int aoff0 = (wr * 64 + (lane & 15)) * 128;
  const int boff0 = (wc * 32 + (lane & 15)) * 128;
  const int kko0  = (((lane >> 4)) ^ (lane & 7)) << 4;
  const int kko1  = ((4 + (lane >> 4)) ^ (lane & 7)) << 4;

  f32x4 acc[2][2][4][2];
#pragma unroll
  for (int qm = 0; qm < 2; ++qm)
#pragma unroll
    for (int qn = 0; qn < 2; ++qn)
#pragma unroll
      for (int mf = 0; mf < 4; ++mf)
#pragma unroll
        for (int nf = 0; nf < 2; ++nf) acc[qm][qn][mf][nf] = (f32x4)0.0f;

  bf16x8 a[4][2], b[2][2];

#define STAGE(mat, h, buf, t) {                                            \
    char* lb_ = (char*)&lds[buf][mat][h][0];                               \
    const char* gb_ = (mat ? gB : gA) + (size_t)(h) * 128 * KB2            \
                      + (size_t)(t) * 128;                                 \
    GLD_LDS16(gb_ + gro0 + scx, lb_ + lt0);                                \
    GLD_LDS16(gb_ + gro1 + scx, lb_ + lt1); }

#define LDA(qm, buf) {                                                     \
    const char* p_ = (const char*)&lds[buf][0][qm][0] + aoff0;             \
    _Pragma("unroll")                                                      \
    for (int mf = 0; mf < 4; ++mf) {                                       \
      a[mf][0] = *(const bf16x8*)(p_ + mf * 2048 + kko0);                  \
      a[mf][1] = *(const bf16x8*)(p_ + mf * 2048 + kko1); } }

#define LDB(qn, buf) {                                                     \
    const char* p_ = (const char*)&lds[buf][1][qn][0] + boff0;             \
    _Pragma("unroll")                                                      \
    for (int nf = 0; nf < 2; ++nf) {                                       \
      b[nf][0] = *(const bf16x8*)(p_ + nf * 2048 + kko0);                  \
      b[nf][1] = *(const bf16x8*)(p_ + nf * 2048 + kko1); } }

#define MMA(qm, qn) {                                                      \
    _Pragma("unroll")                                                      \
    for (int mf = 0; mf < 4; ++mf)                                         \
      _Pragma("unroll")                                                    \
      for (int nf = 0; nf < 2; ++nf) {                                     \
        acc[qm][qn][mf][nf] = __builtin_amdgcn_mfma_f32_16x16x32_bf16(     \
            a[mf][0], b[nf][0], acc[qm][qn][mf][nf], 0, 0, 0);             \
        acc[qm][qn][mf][nf] = __builtin_amdgcn_mfma_f32_16x16x32_bf16(     \
            a[mf][1], b[nf][1], acc[qm][qn][mf][nf], 0, 0, 0); } }

#define SYNC_PRE {                                                         \
    __builtin_amdgcn_s_barrier();                                          \
    asm volatile("s_waitcnt lgkmcnt(0)" ::: "memory");                     \
    __builtin_amdgcn_sched_barrier(0);                                     \
    __builtin_amdgcn_s_setprio(1); }

#define SYNC_PRE12 {                                                       \
    asm volatile("s_waitcnt lgkmcnt(8)" ::: "memory");                     \
    __builtin_amdgcn_s_barrier();                                          \
    asm volatile("s_waitcnt lgkmcnt(0)" ::: "memory");                     \
    __builtin_amdgcn_sched_barrier(0);                                     \
    __builtin_amdgcn_s_setprio(1); }

#define SYNC_POST {                                                        \
    __builtin_amdgcn_s_setprio(0);                                         \
    __builtin_amdgcn_sched_barrier(0);                                     \
    __builtin_amdgcn_s_barrier(); }

#define SYNC_POST_V6 {                                                     \
    __builtin_amdgcn_s_setprio(0);                                         \
    __builtin_amdgcn_sched_barrier(0);                                     \
    asm volatile("s_waitcnt vmcnt(6)" ::: "memory");                       \
    __builtin_amdgcn_s_barrier(); }

  // ---- prologue: t0 fully + A0(1), A1(1), B1(1); drain t0, keep 3 stages
  STAGE(0, 0, 0, 0);  // A0(0)
  STAGE(1, 0, 0, 0);  // B0(0)
  STAGE(1, 1, 0, 0);  // B1(0)
  STAGE(0, 1, 0, 0);  // A1(0)
  STAGE(0, 0, 1, 1);  // A0(1)
  STAGE(0, 1, 1, 1);  // A1(1)
  STAGE(1, 1, 1, 1);  // B1(1)
  asm volatile("s_waitcnt vmcnt(6)" ::: "memory");
  __builtin_amdgcn_s_barrier();

  // ---- main loop: tiles 2i (buf0) and 2i+1 (buf1), i = 0..30
  for (int i = 0; i < 31; ++i) {
    const int t1 = 2 * i + 1, t2 = 2 * i + 2, t3 = 2 * i + 3;
    // ph1: (A0,B0) even tile
    LDA(0, 0); LDB(0, 0); STAGE(1, 0, 1, t1);   // B0(t1)
    SYNC_PRE12; MMA(0, 0); SYNC_POST;
    // ph2: (A0,B1)
    LDB(1, 0); STAGE(0, 0, 0, t2);              // A0(t2)
    SYNC_PRE; MMA(0, 1); SYNC_POST;
    // ph3: (A1,B1)
    LDA(1, 0);
    SYNC_PRE; MMA(1, 1); SYNC_POST;
    // ph4: (A1,B0)
    LDB(0, 0); STAGE(0, 1, 0, t2); STAGE(1, 1, 0, t2);  // A1(t2), B1(t2)
    SYNC_PRE; MMA(1, 0); SYNC_POST_V6;          // t1 resident (B0(t1) 4 phases old)
    // ph5: (A0,B0) odd tile
    LDA(0, 1); LDB(0, 1); STAGE(1, 0, 0, t2);   // B0(t2)
    SYNC_PRE12; MMA(0, 0); SYNC_POST;
    // ph6: (A0,B1)
    LDB(1, 1); STAGE(0, 0, 1, t3);              // A0(t3)
    SYNC_PRE; MMA(0, 1); SYNC_POST;
    // ph7: (A1,B1)
    LDA(1, 1);
    SYNC_PRE; MMA(1, 1); SYNC_POST;
    // ph8: (A1,B0)
    LDB(0, 1); STAGE(0, 1, 1, t3); STAGE(1, 1, 1, t3);  // A1(t3), B1(t3)
    SYNC_PRE; MMA(1, 0); SYNC_POST_V6;          // t2 resident (B0(t2) 4 phases old)
  }

  // ---- tail: tiles 62 (buf0), 63 (buf1); in flight: A0,A1,B1(63)
  LDA(0, 0); LDB(0, 0); STAGE(1, 0, 1, 63);     // B0(63)
  SYNC_PRE12; MMA(0, 0); SYNC_POST;
  LDB(1, 0);
  SYNC_PRE; MMA(0, 1); SYNC_POST;
  LDA(1, 0);
  SYNC_PRE; MMA(1, 1); SYNC_POST;
  LDB(0, 0);
  SYNC_PRE; MMA(1, 0);
  __builtin_amdgcn_s_setprio(0);
  __builtin_amdgcn_sched_barrier(0);
  asm volatile("s_waitcnt vmcnt(0)" ::: "memory");
  __builtin_amdgcn_s_barrier();
  LDA(0, 1); LDB(0, 1);
  SYNC_PRE12; MMA(0, 0); SYNC_POST;
  LDB(1, 1);
  SYNC_PRE; MMA(0, 1); SYNC_POST;
  LDA(1, 1);
  SYNC_PRE; MMA(1, 1); SYNC_POST;
  LDB(0, 1);
  SYNC_PRE; MMA(1, 0);
  __builtin_amdgcn_s_setprio(0);

  // ---- epilogue: C/D layout col=lane&15, row=(lane>>4)*4+j
  const int cL = lane & 15;
  const int rL = (lane >> 4) * 4;
#pragma unroll
  for (int qn = 0; qn < 2; ++qn)
#pragma unroll
    for (int nf = 0; nf < 2; ++nf) {
      int col = nb * 256 + qn * 128 + wc * 32 + nf * 16 + cL;
      float bv = bias[col];
#pragma unroll
      for (int qm = 0; qm < 2; ++qm)
#pragma unroll
        for (int mf = 0; mf < 4; ++mf) {
          int row0 = mb * 256 + qm * 128 + wr * 64 + mf * 16 + rL;
#pragma unroll
          for (int j = 0; j < 4; ++j)
            C[(size_t)(row0 + j) * N_DIM + col] = acc[qm][qn][mf][nf][j] + bv;
        }
    }
#undef STAGE
#undef LDA
#undef LDB
#undef MMA
#undef SYNC_PRE
#undef SYNC_PRE12
#undef SYNC_POST
#undef SYNC_POST_V6
}

extern "C" void kernel_launch(void* const* d_in, const int* in_sizes, int n_in,
                              void* d_out, int out_size, void* d_ws, size_t ws_size,
                              hipStream_t stream) {
  const float* x    = (const float*)d_in[0];
  const int*   qw   = (const int*)d_in[1];
  const float* lut  = (const float*)d_in[2];
  const float* bias = (const float*)d_in[3];

  __bf16* Wb = (__bf16*)d_ws;
  __bf16* Xb = (__bf16*)((char*)d_ws + (size_t)N_DIM * K_DIM * 2);

  {
    int total = N_DIM * (K_DIM / 32);
    anyprec_dequant_kernel<<<total / 256, 256, 0, stream>>>(qw, lut, Wb);
  }
  {
    int n8 = (M_DIM * K_DIM) / 8;
    cvt_x_kernel<<<(n8 + 255) / 256, 256, 0, stream>>>(x, Xb, n8);
  }
  {
    dim3 grid((M_DIM / 256) * (N_DIM / 256));  // 32*16 = 512
    anyprec_gemm_kernel<<<grid, 512, 0, stream>>>(Xb, Wb, bias, (float*)d_out);
  }
}

// Round 4
// 273.917 us; speedup vs baseline: 1.0322x; 1.0322x over previous
//
#include <hip/hip_runtime.h>
#include <hip/hip_bf16.h>
#include <stdint.h>

#define M_DIM 8192   // 4*2048
#define N_DIM 4096   // OUT_FEATURES
#define K_DIM 4096   // IN_FEATURES
#define KB2   (K_DIM * 2)   // bytes per K-row

typedef __attribute__((ext_vector_type(8))) __bf16 bf16x8;
typedef __attribute__((ext_vector_type(4))) float  f32x4;

#define GLD_LDS16(gaddr, laddr)                                            \
  __builtin_amdgcn_global_load_lds(                                        \
      (const __attribute__((address_space(1))) uint32_t*)(gaddr),          \
      (__attribute__((address_space(3))) uint32_t*)(laddr), 16, 0, 0)

// ---------------------------------------------------------------------------
// Dequant: qweight (8, O, 128) int32 bit-planes + lut (O,16) -> Wb (O,K) bf16
// ---------------------------------------------------------------------------
__global__ __launch_bounds__(256) void anyprec_dequant_kernel(
    const int* __restrict__ q, const float* __restrict__ lut,
    __bf16* __restrict__ Wb) {
  int t = blockIdx.x * 256 + threadIdx.x;   // 0 .. O*128-1
  int o = t >> 7;
  int w = t & 127;
  const int PLANE = N_DIM * (K_DIM / 32);
  int base = o * (K_DIM / 32) + w;
  uint32_t q0 = (uint32_t)q[0 * PLANE + base];
  uint32_t q1 = (uint32_t)q[1 * PLANE + base];
  uint32_t q2 = (uint32_t)q[2 * PLANE + base];
  uint32_t q3 = (uint32_t)q[3 * PLANE + base];
  const float* lrow = lut + o * 16;

  __bf16 vals[32];
#pragma unroll
  for (int i = 0; i < 32; ++i) {
    uint32_t idx = ((q0 >> i) & 1u) | (((q1 >> i) & 1u) << 1) |
                   (((q2 >> i) & 1u) << 2) | (((q3 >> i) & 1u) << 3);
    vals[i] = (__bf16)lrow[idx];
  }
  bf16x8* dst = (bf16x8*)(Wb + (size_t)o * K_DIM + w * 32);
#pragma unroll
  for (int r = 0; r < 4; ++r) {
    bf16x8 v;
#pragma unroll
    for (int j = 0; j < 8; ++j) v[j] = vals[r * 8 + j];
    dst[r] = v;
  }
}

// ---------------------------------------------------------------------------
// x fp32 -> bf16
// ---------------------------------------------------------------------------
__global__ __launch_bounds__(256) void cvt_x_kernel(
    const float* __restrict__ x, __bf16* __restrict__ xb, int n8) {
  int t = blockIdx.x * 256 + threadIdx.x;
  if (t >= n8) return;
  f32x4 a = ((const f32x4*)x)[t * 2];
  f32x4 b = ((const f32x4*)x)[t * 2 + 1];
  bf16x8 v;
  v[0] = (__bf16)a[0]; v[1] = (__bf16)a[1]; v[2] = (__bf16)a[2]; v[3] = (__bf16)a[3];
  v[4] = (__bf16)b[0]; v[5] = (__bf16)b[1]; v[6] = (__bf16)b[2]; v[7] = (__bf16)b[3];
  ((bf16x8*)xb)[t] = v;
}

// ---------------------------------------------------------------------------
// 256x256 8-phase bf16 GEMM: C[M,N] = A[M,K] * B[N,K]^T + bias (fp32 out)
// 512 thr = 8 waves (2M x 4N). BK=64. LDS 128 KiB: [buf][A/B][half][128x64].
// R4: relaxed lgkm (compiler fine-grained waits overlap LDS drain with MFMA);
// b0/b1 persist in regs across the tile (24 ds_read_b128/wave/tile);
// exactly 1 half-tile STAGE per phase; vmcnt(6) drains at ph4/ph8 only.
//   stages: ph1=B0(o) ph2=A0(e+) ph3=B1(e+) ph4=A1(e+)
//           ph5=B0(e+) ph6=A0(o+) ph7=B1(o+) ph8=A1(o+)
// ---------------------------------------------------------------------------
__global__ __launch_bounds__(512, 2) void anyprec_gemm_kernel(
    const __bf16* __restrict__ A,   // M x K bf16
    const __bf16* __restrict__ B,   // N x K bf16
    const float* __restrict__ bias,
    float* __restrict__ C) {
  __shared__ __bf16 lds[2][2][2][128 * 64];   // 131072 B

  // XCD-aware bijective swizzle (512 wgs, 512%8==0)
  int bid = blockIdx.x;
  int swz = (bid & 7) * 64 + (bid >> 3);
  int mb = swz >> 4;    // 32 m-tiles
  int nb = swz & 15;    // 16 n-tiles

  const int tid  = threadIdx.x;
  const int lane = tid & 63;
  const int wid  = tid >> 6;
  const int wr   = wid >> 2;   // 0..1
  const int wc   = wid & 3;    // 0..3

  const char* gA = (const char*)A + (size_t)mb * 256 * KB2;
  const char* gB = (const char*)B + (size_t)nb * 256 * KB2;
  const size_t gro0 = (size_t)(tid >> 3) * KB2;       // row  = chunk>>3
  const size_t gro1 = gro0 + (size_t)64 * KB2;        // row + 64
  const int    scx  = (((tid & 7) ^ ((tid >> 3) & 7)) << 4);  // swizzled src chunk
  const int    lt0  = tid * 16;
  const int    lt1  = tid * 16 + 8192;

  const int aoff0 = (wr * 64 + (lane & 15)) * 128;
  const int boff0 = (wc * 32 + (lane & 15)) * 128;
  const int kko0  = (((lane >> 4)) ^ (lane & 7)) << 4;
  const int kko1  = ((4 + (lane >> 4)) ^ (lane & 7)) << 4;

  f32x4 acc[2][2][4][2];
#pragma unroll
  for (int qm = 0; qm < 2; ++qm)
#pragma unroll
    for (int qn = 0; qn < 2; ++qn)
#pragma unroll
      for (int mf = 0; mf < 4; ++mf)
#pragma unroll
        for (int nf = 0; nf < 2; ++nf) acc[qm][qn][mf][nf] = (f32x4)0.0f;

  bf16x8 a[4][2], b0[2][2], b1[2][2];

#define STAGE(mat, h, buf, t) {                                            \
    char* lb_ = (char*)&lds[buf][mat][h][0];                               \
    const char* gb_ = (mat ? gB : gA) + (size_t)(h) * 128 * KB2            \
                      + (size_t)(t) * 128;                                 \
    GLD_LDS16(gb_ + gro0 + scx, lb_ + lt0);                                \
    GLD_LDS16(gb_ + gro1 + scx, lb_ + lt1); }

#define LDA(qm, buf) {                                                     \
    const char* p_ = (const char*)&lds[buf][0][qm][0] + aoff0;             \
    _Pragma("unroll")                                                      \
    for (int mf = 0; mf < 4; ++mf) {                                       \
      a[mf][0] = *(const bf16x8*)(p_ + mf * 2048 + kko0);                  \
      a[mf][1] = *(const bf16x8*)(p_ + mf * 2048 + kko1); } }

#define LDB(dst, qn, buf) {                                                \
    const char* p_ = (const char*)&lds[buf][1][qn][0] + boff0;             \
    _Pragma("unroll")                                                      \
    for (int nf = 0; nf < 2; ++nf) {                                       \
      dst[nf][0] = *(const bf16x8*)(p_ + nf * 2048 + kko0);                \
      dst[nf][1] = *(const bf16x8*)(p_ + nf * 2048 + kko1); } }

#define MMA(qm, qn, bb) {                                                  \
    _Pragma("unroll")                                                      \
    for (int mf = 0; mf < 4; ++mf)                                         \
      _Pragma("unroll")                                                    \
      for (int nf = 0; nf < 2; ++nf) {                                     \
        acc[qm][qn][mf][nf] = __builtin_amdgcn_mfma_f32_16x16x32_bf16(     \
            a[mf][0], bb[nf][0], acc[qm][qn][mf][nf], 0, 0, 0);            \
        acc[qm][qn][mf][nf] = __builtin_amdgcn_mfma_f32_16x16x32_bf16(     \
            a[mf][1], bb[nf][1], acc[qm][qn][mf][nf], 0, 0, 0); } }

// relaxed: no forced lgkmcnt(0) -- compiler emits fine-grained waits,
// tail ds_reads drain under the MFMA cluster.
#define BARS {                                                             \
    __builtin_amdgcn_s_barrier();                                          \
    __builtin_amdgcn_s_setprio(1); }

#define POSTB {                                                            \
    __builtin_amdgcn_s_setprio(0);                                         \
    __builtin_amdgcn_s_barrier(); }

#define POSTV6 {                                                           \
    __builtin_amdgcn_s_setprio(0);                                         \
    asm volatile("s_waitcnt vmcnt(6)" ::: "memory");                       \
    __builtin_amdgcn_s_barrier(); }

  // ---- prologue: tile0 fully + A0(1), B1(1), A1(1); drain tile0 (8 loads)
  STAGE(0, 0, 0, 0);  // A0(0)
  STAGE(1, 0, 0, 0);  // B0(0)
  STAGE(1, 1, 0, 0);  // B1(0)
  STAGE(0, 1, 0, 0);  // A1(0)
  STAGE(0, 0, 1, 1);  // A0(1)
  STAGE(1, 1, 1, 1);  // B1(1)
  STAGE(0, 1, 1, 1);  // A1(1)
  asm volatile("s_waitcnt vmcnt(6)" ::: "memory");
  __builtin_amdgcn_s_barrier();

  // ---- main loop: tiles 2i (buf0) and 2i+1 (buf1), i = 0..30
  for (int i = 0; i < 31; ++i) {
    const int t1 = 2 * i + 1, t2 = 2 * i + 2, t3 = 2 * i + 3;
    // ph1: (A0,B0) even tile
    STAGE(1, 0, 1, t1);                 // B0(odd)
    LDB(b0, 0, 0); LDA(0, 0);
    BARS; MMA(0, 0, b0); POSTB;
    // ph2: (A0,B1)
    STAGE(0, 0, 0, t2);                 // A0(even+)
    LDB(b1, 1, 0);
    BARS; MMA(0, 1, b1); POSTB;
    // ph3: (A1,B1)
    STAGE(1, 1, 0, t2);                 // B1(even+)
    LDA(1, 0);
    BARS; MMA(1, 1, b1); POSTB;
    // ph4: (A1,B0) -- b0 persisted, no reads
    STAGE(0, 1, 0, t2);                 // A1(even+)
    BARS; MMA(1, 0, b0); POSTV6;        // odd tile resident
    // ph5: (A0,B0) odd tile
    STAGE(1, 0, 0, t2);                 // B0(even+)
    LDB(b0, 0, 1); LDA(0, 1);
    BARS; MMA(0, 0, b0); POSTB;
    // ph6: (A0,B1)
    STAGE(0, 0, 1, t3);                 // A0(odd+)
    LDB(b1, 1, 1);
    BARS; MMA(0, 1, b1); POSTB;
    // ph7: (A1,B1)
    STAGE(1, 1, 1, t3);                 // B1(odd+)
    LDA(1, 1);
    BARS; MMA(1, 1, b1); POSTB;
    // ph8: (A1,B0)
    STAGE(0, 1, 1, t3);                 // A1(odd+)
    BARS; MMA(1, 0, b0); POSTV6;        // next even tile resident
  }

  // ---- tail: tiles 62 (buf0), 63 (buf1); in flight: A0,B1,A1(63)
  STAGE(1, 0, 1, 63);                   // B0(63)
  LDB(b0, 0, 0); LDA(0, 0);
  BARS; MMA(0, 0, b0); POSTB;
  LDB(b1, 1, 0);
  BARS; MMA(0, 1, b1); POSTB;
  LDA(1, 0);
  BARS; MMA(1, 1, b1); MMA(1, 0, b0);
  __builtin_amdgcn_s_setprio(0);
  asm volatile("s_waitcnt vmcnt(0)" ::: "memory");
  __builtin_amdgcn_s_barrier();
  LDB(b0, 0, 1); LDA(0, 1);
  BARS; MMA(0, 0, b0); POSTB;
  LDB(b1, 1, 1);
  BARS; MMA(0, 1, b1); POSTB;
  LDA(1, 1);
  BARS; MMA(1, 1, b1); MMA(1, 0, b0);
  __builtin_amdgcn_s_setprio(0);

  // ---- epilogue: C/D layout col=lane&15, row=(lane>>4)*4+j
  const int cL = lane & 15;
  const int rL = (lane >> 4) * 4;
#pragma unroll
  for (int qn = 0; qn < 2; ++qn)
#pragma unroll
    for (int nf = 0; nf < 2; ++nf) {
      int col = nb * 256 + qn * 128 + wc * 32 + nf * 16 + cL;
      float bv = bias[col];
#pragma unroll
      for (int qm = 0; qm < 2; ++qm)
#pragma unroll
        for (int mf = 0; mf < 4; ++mf) {
          int row0 = mb * 256 + qm * 128 + wr * 64 + mf * 16 + rL;
#pragma unroll
          for (int j = 0; j < 4; ++j)
            C[(size_t)(row0 + j) * N_DIM + col] = acc[qm][qn][mf][nf][j] + bv;
        }
    }
#undef STAGE
#undef LDA
#undef LDB
#undef MMA
#undef BARS
#undef POSTB
#undef POSTV6
}

extern "C" void kernel_launch(void* const* d_in, const int* in_sizes, int n_in,
                              void* d_out, int out_size, void* d_ws, size_t ws_size,
                              hipStream_t stream) {
  const float* x    = (const float*)d_in[0];
  const int*   qw   = (const int*)d_in[1];
  const float* lut  = (const float*)d_in[2];
  const float* bias = (const float*)d_in[3];

  __bf16* Wb = (__bf16*)d_ws;
  __bf16* Xb = (__bf16*)((char*)d_ws + (size_t)N_DIM * K_DIM * 2);

  {
    int total = N_DIM * (K_DIM / 32);
    anyprec_dequant_kernel<<<total / 256, 256, 0, stream>>>(qw, lut, Wb);
  }
  {
    int n8 = (M_DIM * K_DIM) / 8;
    cvt_x_kernel<<<(n8 + 255) / 256, 256, 0, stream>>>(x, Xb, n8);
  }
  {
    dim3 grid((M_DIM / 256) * (N_DIM / 256));  // 32*16 = 512
    anyprec_gemm_kernel<<<grid, 512, 0, stream>>>(Xb, Wb, bias, (float*)d_out);
  }
}

// Round 5
// 265.151 us; speedup vs baseline: 1.0664x; 1.0331x over previous
//
#include <hip/hip_runtime.h>
#include <hip/hip_bf16.h>
#include <stdint.h>

#define M_DIM 8192   // 4*2048
#define N_DIM 4096   // OUT_FEATURES
#define K_DIM 4096   // IN_FEATURES
#define KB2   (K_DIM * 2)   // bytes per K-row

typedef __attribute__((ext_vector_type(8))) __bf16 bf16x8;
typedef __attribute__((ext_vector_type(4))) float  f32x4;

#define GLD_LDS16(gaddr, laddr)                                            \
  __builtin_amdgcn_global_load_lds(                                        \
      (const __attribute__((address_space(1))) uint32_t*)(gaddr),          \
      (__attribute__((address_space(3))) uint32_t*)(laddr), 16, 0, 0)

// ---------------------------------------------------------------------------
// Dequant: qweight (8, O, 128) int32 bit-planes + lut (O,16) -> Wb (O,K) bf16
// ---------------------------------------------------------------------------
__global__ __launch_bounds__(256) void anyprec_dequant_kernel(
    const int* __restrict__ q, const float* __restrict__ lut,
    __bf16* __restrict__ Wb) {
  int t = blockIdx.x * 256 + threadIdx.x;   // 0 .. O*128-1
  int o = t >> 7;
  int w = t & 127;
  const int PLANE = N_DIM * (K_DIM / 32);
  int base = o * (K_DIM / 32) + w;
  uint32_t q0 = (uint32_t)q[0 * PLANE + base];
  uint32_t q1 = (uint32_t)q[1 * PLANE + base];
  uint32_t q2 = (uint32_t)q[2 * PLANE + base];
  uint32_t q3 = (uint32_t)q[3 * PLANE + base];
  const float* lrow = lut + o * 16;

  __bf16 vals[32];
#pragma unroll
  for (int i = 0; i < 32; ++i) {
    uint32_t idx = ((q0 >> i) & 1u) | (((q1 >> i) & 1u) << 1) |
                   (((q2 >> i) & 1u) << 2) | (((q3 >> i) & 1u) << 3);
    vals[i] = (__bf16)lrow[idx];
  }
  bf16x8* dst = (bf16x8*)(Wb + (size_t)o * K_DIM + w * 32);
#pragma unroll
  for (int r = 0; r < 4; ++r) {
    bf16x8 v;
#pragma unroll
    for (int j = 0; j < 8; ++j) v[j] = vals[r * 8 + j];
    dst[r] = v;
  }
}

// ---------------------------------------------------------------------------
// x fp32 -> bf16
// ---------------------------------------------------------------------------
__global__ __launch_bounds__(256) void cvt_x_kernel(
    const float* __restrict__ x, __bf16* __restrict__ xb, int n8) {
  int t = blockIdx.x * 256 + threadIdx.x;
  if (t >= n8) return;
  f32x4 a = ((const f32x4*)x)[t * 2];
  f32x4 b = ((const f32x4*)x)[t * 2 + 1];
  bf16x8 v;
  v[0] = (__bf16)a[0]; v[1] = (__bf16)a[1]; v[2] = (__bf16)a[2]; v[3] = (__bf16)a[3];
  v[4] = (__bf16)b[0]; v[5] = (__bf16)b[1]; v[6] = (__bf16)b[2]; v[7] = (__bf16)b[3];
  ((bf16x8*)xb)[t] = v;
}

// ---------------------------------------------------------------------------
// 256x256 bf16 GEMM, 8-phase, REGISTER-PIPELINED (R5):
// ds_reads for phase p+1 are issued inside phase p's MFMA cluster, so the
// LDS pipe (576 cyc/phase) drains under the MFMA pipe (621 cyc/phase).
// One barrier per phase. Tile-residency drains vmcnt(4) at p3/p7.
// Reg liveness (verified): a0 loaded p8',used p1-2,ovw p4; a1 loaded p2,
// used p3-4,ovw p6; b0 loaded p8',used p1&p4,ovw p4(after use); b1 loaded
// p1,used p2-3,ovw p5. Mirrored for odd tile. Every STAGE overwrites a
// region whose last ds_read was lgkm-consumed >=1 barrier earlier.
// ---------------------------------------------------------------------------
__global__ __launch_bounds__(512, 2) void anyprec_gemm_kernel(
    const __bf16* __restrict__ A,   // M x K bf16
    const __bf16* __restrict__ B,   // N x K bf16
    const float* __restrict__ bias,
    float* __restrict__ C) {
  __shared__ __bf16 lds[2][2][2][128 * 64];   // 131072 B

  // XCD-aware bijective swizzle (512 wgs, 512%8==0)
  int bid = blockIdx.x;
  int swz = (bid & 7) * 64 + (bid >> 3);
  int mb = swz >> 4;    // 32 m-tiles
  int nb = swz & 15;    // 16 n-tiles

  const int tid  = threadIdx.x;
  const int lane = tid & 63;
  const int wid  = tid >> 6;
  const int wr   = wid >> 2;   // 0..1
  const int wc   = wid & 3;    // 0..3

  const char* gA = (const char*)A + (size_t)mb * 256 * KB2;
  const char* gB = (const char*)B + (size_t)nb * 256 * KB2;
  const size_t gro0 = (size_t)(tid >> 3) * KB2;       // row  = chunk>>3
  const size_t gro1 = gro0 + (size_t)64 * KB2;        // row + 64
  const int    scx  = (((tid & 7) ^ ((tid >> 3) & 7)) << 4);  // swizzled src chunk
  const int    lt0  = tid * 16;
  const int    lt1  = tid * 16 + 8192;

  const int aoff0 = (wr * 64 + (lane & 15)) * 128;
  const int boff0 = (wc * 32 + (lane & 15)) * 128;
  const int kko0  = (((lane >> 4)) ^ (lane & 7)) << 4;
  const int kko1  = ((4 + (lane >> 4)) ^ (lane & 7)) << 4;

  f32x4 acc[2][2][4][2];
#pragma unroll
  for (int qm = 0; qm < 2; ++qm)
#pragma unroll
    for (int qn = 0; qn < 2; ++qn)
#pragma unroll
      for (int mf = 0; mf < 4; ++mf)
#pragma unroll
        for (int nf = 0; nf < 2; ++nf) acc[qm][qn][mf][nf] = (f32x4)0.0f;

  bf16x8 a0[4][2], a1[4][2], b0[2][2], b1[2][2];

#define STAGE(mat, h, buf, t) {                                            \
    char* lb_ = (char*)&lds[buf][mat][h][0];                               \
    const char* gb_ = (mat ? gB : gA) + (size_t)(h) * 128 * KB2            \
                      + (size_t)(t) * 128;                                 \
    GLD_LDS16(gb_ + gro0 + scx, lb_ + lt0);                                \
    GLD_LDS16(gb_ + gro1 + scx, lb_ + lt1); }

#define LDA(dst, qm, buf) {                                                \
    const char* p_ = (const char*)&lds[buf][0][qm][0] + aoff0;             \
    _Pragma("unroll")                                                      \
    for (int mf = 0; mf < 4; ++mf) {                                       \
      dst[mf][0] = *(const bf16x8*)(p_ + mf * 2048 + kko0);                \
      dst[mf][1] = *(const bf16x8*)(p_ + mf * 2048 + kko1); } }

#define LDB(dst, qn, buf) {                                                \
    const char* p_ = (const char*)&lds[buf][1][qn][0] + boff0;             \
    _Pragma("unroll")                                                      \
    for (int nf = 0; nf < 2; ++nf) {                                       \
      dst[nf][0] = *(const bf16x8*)(p_ + nf * 2048 + kko0);                \
      dst[nf][1] = *(const bf16x8*)(p_ + nf * 2048 + kko1); } }

#define MMA(qm, qn, aa, bb) {                                              \
    _Pragma("unroll")                                                      \
    for (int mf = 0; mf < 4; ++mf)                                         \
      _Pragma("unroll")                                                    \
      for (int nf = 0; nf < 2; ++nf) {                                     \
        acc[qm][qn][mf][nf] = __builtin_amdgcn_mfma_f32_16x16x32_bf16(     \
            aa[mf][0], bb[nf][0], acc[qm][qn][mf][nf], 0, 0, 0);           \
        acc[qm][qn][mf][nf] = __builtin_amdgcn_mfma_f32_16x16x32_bf16(     \
            aa[mf][1], bb[nf][1], acc[qm][qn][mf][nf], 0, 0, 0); } }

#define PRIO1 __builtin_amdgcn_s_setprio(1);
#define PRIO0 __builtin_amdgcn_s_setprio(0);
#define BAR   __builtin_amdgcn_s_barrier();
#define VMC4  asm volatile("s_waitcnt vmcnt(4)" ::: "memory");
#define VMC0  asm volatile("s_waitcnt vmcnt(0)" ::: "memory");
#define VMC6  asm volatile("s_waitcnt vmcnt(6)" ::: "memory");

  // ---- prologue: stage tile0 + A0,B1,A1 of tile1; certify tile0; preload regs
  STAGE(0, 0, 0, 0);  // A0(0)
  STAGE(1, 0, 0, 0);  // B0(0)
  STAGE(1, 1, 0, 0);  // B1(0)
  STAGE(0, 1, 0, 0);  // A1(0)
  STAGE(0, 0, 1, 1);  // A0(1)
  STAGE(1, 1, 1, 1);  // B1(1)
  STAGE(0, 1, 1, 1);  // A1(1)
  VMC6; BAR;
  LDA(a0, 0, 0); LDB(b0, 0, 0);   // consumed in p1 (lgkm auto-wait)

  // ---- main loop: tiles E=2i (buf0), O=2i+1 (buf1), i = 0..30
  for (int i = 0; i < 31; ++i) {
    const int t1 = 2 * i + 1, t2 = 2 * i + 2, t3 = 2 * i + 3;
    // p1: MMA(0,0)E ; load B1(E) ; stage B0(O)
    STAGE(1, 0, 1, t1);
    PRIO1; LDB(b1, 1, 0); MMA(0, 0, a0, b0); PRIO0; BAR;
    // p2: MMA(0,1)E ; load A1(E) ; stage A0(E+2)
    STAGE(0, 0, 0, t2);
    PRIO1; LDA(a1, 1, 0); MMA(0, 1, a0, b1); PRIO0; BAR;
    // p3: MMA(1,1)E ; stage B1(E+2) ; certify tile O
    STAGE(1, 1, 0, t2);
    PRIO1; MMA(1, 1, a1, b1); PRIO0; VMC4; BAR;
    // p4: MMA(1,0)E ; load A0(O), B0(O) (B0 after MMA: WAR) ; stage A1(E+2)
    STAGE(0, 1, 0, t2);
    PRIO1; LDA(a0, 0, 1); MMA(1, 0, a1, b0); LDB(b0, 0, 1); PRIO0; BAR;
    // p5: MMA(0,0)O ; load B1(O) ; stage B0(E+2)
    STAGE(1, 0, 0, t2);
    PRIO1; LDB(b1, 1, 1); MMA(0, 0, a0, b0); PRIO0; BAR;
    // p6: MMA(0,1)O ; load A1(O) ; stage A0(O+2)
    STAGE(0, 0, 1, t3);
    PRIO1; LDA(a1, 1, 1); MMA(0, 1, a0, b1); PRIO0; BAR;
    // p7: MMA(1,1)O ; stage B1(O+2) ; certify tile E+2
    STAGE(1, 1, 1, t3);
    PRIO1; MMA(1, 1, a1, b1); PRIO0; VMC4; BAR;
    // p8: MMA(1,0)O ; load A0(E+2), B0(E+2) ; stage A1(O+2)
    STAGE(0, 1, 1, t3);
    PRIO1; LDA(a0, 0, 0); MMA(1, 0, a1, b0); LDB(b0, 0, 0); PRIO0; BAR;
  }

  // ---- tail: tiles 62 (buf0), 63 (buf1); regs hold A0(62),B0(62);
  //      outstanding stages: A0(63),B1(63),A1(63)
  STAGE(1, 0, 1, 63);                         // B0(63)
  PRIO1; LDB(b1, 1, 0); MMA(0, 0, a0, b0); PRIO0; BAR;
  PRIO1; LDA(a1, 1, 0); MMA(0, 1, a0, b1); PRIO0; BAR;
  PRIO1; MMA(1, 1, a1, b1); PRIO0; VMC0; BAR; // tile 63 fully resident
  PRIO1; LDA(a0, 0, 1); MMA(1, 0, a1, b0); LDB(b0, 0, 1); PRIO0; BAR;
  PRIO1; LDB(b1, 1, 1); MMA(0, 0, a0, b0); PRIO0; BAR;
  PRIO1; LDA(a1, 1, 1); MMA(0, 1, a0, b1); PRIO0; BAR;
  MMA(1, 1, a1, b1);
  MMA(1, 0, a1, b0);

  // ---- epilogue: C/D layout col=lane&15, row=(lane>>4)*4+j
  const int cL = lane & 15;
  const int rL = (lane >> 4) * 4;
#pragma unroll
  for (int qn = 0; qn < 2; ++qn)
#pragma unroll
    for (int nf = 0; nf < 2; ++nf) {
      int col = nb * 256 + qn * 128 + wc * 32 + nf * 16 + cL;
      float bv = bias[col];
#pragma unroll
      for (int qm = 0; qm < 2; ++qm)
#pragma unroll
        for (int mf = 0; mf < 4; ++mf) {
          int row0 = mb * 256 + qm * 128 + wr * 64 + mf * 16 + rL;
#pragma unroll
          for (int j = 0; j < 4; ++j)
            C[(size_t)(row0 + j) * N_DIM + col] = acc[qm][qn][mf][nf][j] + bv;
        }
    }
#undef STAGE
#undef LDA
#undef LDB
#undef MMA
#undef PRIO1
#undef PRIO0
#undef BAR
#undef VMC4
#undef VMC0
#undef VMC6
}

extern "C" void kernel_launch(void* const* d_in, const int* in_sizes, int n_in,
                              void* d_out, int out_size, void* d_ws, size_t ws_size,
                              hipStream_t stream) {
  const float* x    = (const float*)d_in[0];
  const int*   qw   = (const int*)d_in[1];
  const float* lut  = (const float*)d_in[2];
  const float* bias = (const float*)d_in[3];

  __bf16* Wb = (__bf16*)d_ws;
  __bf16* Xb = (__bf16*)((char*)d_ws + (size_t)N_DIM * K_DIM * 2);

  {
    int total = N_DIM * (K_DIM / 32);
    anyprec_dequant_kernel<<<total / 256, 256, 0, stream>>>(qw, lut, Wb);
  }
  {
    int n8 = (M_DIM * K_DIM) / 8;
    cvt_x_kernel<<<(n8 + 255) / 256, 256, 0, stream>>>(x, Xb, n8);
  }
  {
    dim3 grid((M_DIM / 256) * (N_DIM / 256));  // 32*16 = 512
    anyprec_gemm_kernel<<<grid, 512, 0, stream>>>(Xb, Wb, bias, (float*)d_out);
  }
}